// Round 2
// baseline (202.560 us; speedup 1.0000x reference)
//
#include <hip/hip_runtime.h>
#include <hip/hip_cooperative_groups.h>

#define BD 128   // D
#define SL 512   // L
#define NB 4     // B

namespace cg = cooperative_groups;

__device__ __forceinline__ float rcp_fast(float x) { return __builtin_amdgcn_rcpf(x); }

// ===================== fused single-launch cooperative path =====================
// Theory: per-dispatch overhead (~10us/kernel) dominates the controllable time.
// One kernel, one grid.sync(). Transpose kernel eliminated: QK phase puts lanes
// along rows (wave = 64 rows), so W is consumed row-contiguous via wave-uniform
// scalar loads -> no WT needed at all.

struct QkMem { float x[64][130]; float e[16][65]; };      // 37,440 B
struct AtMem {
    float4 E2[32][4];        // [c][i]: Ekw[i0+i][4c..4c+3] * u    (2 KB)
    float4 u4[32];           // u[4c..4c+3] = 1/wv                 (0.5 KB)
    float4 pT[SL];           // attn row-quad per j                (8 KB)
    float  fin[32 * BD];     // P3 partials [g*4+row][d]           (16 KB)
    float4 red[8];           // per-wave softmax partial sums      (128 B)
};                           // 27,264 B

__global__ __launch_bounds__(512, 4) void k_fused(const float* __restrict__ inp,
                                                  const float* __restrict__ Wu,
                                                  const float* __restrict__ Ww,
                                                  const float* __restrict__ Wv,
                                                  float* __restrict__ Equ,
                                                  float* __restrict__ Ekw,
                                                  float* __restrict__ out,
                                                  float* __restrict__ attn) {
    constexpr size_t SM_BYTES = sizeof(QkMem) > sizeof(AtMem) ? sizeof(QkMem) : sizeof(AtMem);
    __shared__ __align__(16) unsigned char smraw[SM_BYTES];
    QkMem& qk = *reinterpret_cast<QkMem*>(smraw);
    AtMem& at = *reinterpret_cast<AtMem*>(smraw);

    const int t   = threadIdx.x;
    const int blk = blockIdx.x;
    const int x   = blk & 7;           // XCD (round-robin heuristic)
    const int b   = x >> 1;            // batch pinned to XCD pair (both phases!)

    // ---------------- phase QK: qu = inp@Wu.T, kw = inp@Ww.T ----------------
    // Per batch 128 jobs: jb = {m, o-slab of 16, row-chunk of 64}. Wave = 64 rows
    // (lanes), 2 outputs o per wave -> W rows read wave-uniform (scalar cache).
    {
        const int jb = ((blk >> 3) << 1) | (x & 1);  // 0..127 within batch
        const int m  = jb & 1;                       // 0: Wu->Equ, 1: Ww->Ekw
        const int o0 = ((jb >> 1) & 7) << 4;         // o slab base 0,16,..,112
        const int rc = jb >> 4;                      // row chunk 0..7
        const int R0 = b * SL + rc * 64;             // global row base

        #pragma unroll
        for (int c = 0; c < 16; ++c) {               // stage 64 rows, coalesced
            int lin = c * 512 + t;
            qk.x[lin >> 7][lin & 127] = inp[(size_t)R0 * BD + lin];
        }
        __syncthreads();

        const int w = t >> 6, l = t & 63;            // wave id, lane = row
        const int ou = __builtin_amdgcn_readfirstlane(o0 + (w << 1));
        const float* __restrict__ Wm = m ? Ww : Wu;
        const float* __restrict__ W0 = Wm + (size_t)ou * BD;   // row-contiguous!
        const float* __restrict__ W1 = W0 + BD;
        float acc0 = 0.f, acc1 = 0.f;
        #pragma unroll 8
        for (int k = 0; k < BD; k += 2) {
            float2 xv = *(const float2*)&qk.x[l][k];  // b64, 2-way bank = free
            float wa0 = W0[k], wb0 = W0[k + 1];       // wave-uniform scalar loads
            float wa1 = W1[k], wb1 = W1[k + 1];
            acc0 = fmaf(xv.x, wa0, acc0); acc0 = fmaf(xv.y, wb0, acc0);
            acc1 = fmaf(xv.x, wa1, acc1); acc1 = fmaf(xv.y, wb1, acc1);
        }
        qk.e[(w << 1) + 0][l] = __expf(2.f * acc0);   // LDS transpose stage
        qk.e[(w << 1) + 1][l] = __expf(2.f * acc1);
        __syncthreads();

        if (m) {
            // Ekw[b,row][o]: 16-float row segments, coalesced
            #pragma unroll
            for (int ph = 0; ph < 2; ++ph) {
                int e   = ph * 512 + t;
                int row = e >> 4, ol = e & 15;
                Ekw[(size_t)(R0 + row) * BD + o0 + ol] = qk.e[ol][row];
            }
        } else {
            // Equ[b][c][j][kk] packed layout, fully coalesced 256B runs
            float* Eb = Equ + (((size_t)b * 32 + (o0 >> 2)) * SL + rc * 64) * 4;
            #pragma unroll
            for (int ph = 0; ph < 2; ++ph) {
                int e  = ph * 512 + t;
                int cL = e >> 8, lj = (e >> 2) & 63, kk = e & 3;
                Eb[((size_t)cL * SL + lj) * 4 + kk] = qk.e[cL * 4 + kk][lj];
            }
        }
    }

    __threadfence();            // cross-XCD visibility insurance
    cg::this_grid().sync();     // the ONE grid-wide barrier

    // ---------------- phase ATTN (round-1 body, proven) ----------------
    const int it = ((blk >> 3) << 1) | (x & 1);   // i-tile 0..127
    const int i0 = it * 4;
    const int j  = t;                             // key index 0..511

    if (j < BD) {
        const float* ek = Ekw + ((size_t)b * SL + i0) * BD + j;
        float u = rcp_fast(Wv[j]);
        int c = j >> 2, kk = j & 3;
        ((float*)&at.E2[c][0])[kk] = ek[0]      * u;
        ((float*)&at.E2[c][1])[kk] = ek[BD]     * u;
        ((float*)&at.E2[c][2])[kk] = ek[2 * BD] * u;
        ((float*)&at.E2[c][3])[kk] = ek[3 * BD] * u;
        ((float*)&at.u4[c])[kk]    = u;
    }
    __syncthreads();                                         // B1

    // ---- Phase 1: a_i = sum_d 1/x_d, fully in registers ----
    const float4* equ4 = (const float4*)(Equ) + (size_t)b * 32 * SL;
    float a0 = 0.f, a1 = 0.f, a2 = 0.f, a3 = 0.f;
    #pragma unroll 4
    for (int c = 0; c < 32; ++c) {
        float4 q  = equ4[c * SL + j];      // coalesced, L2-local
        float4 u4 = at.u4[c];              // wave-uniform b128 broadcasts
        float4 e0 = at.E2[c][0];
        float4 e1 = at.E2[c][1];
        float4 e2 = at.E2[c][2];
        float4 e3 = at.E2[c][3];
        // quad-rcp: acc += sum of four reciprocals with one v_rcp
        {
            float x0 = fmaf(q.x, e0.x, u4.x), x1 = fmaf(q.y, e0.y, u4.y);
            float x2 = fmaf(q.z, e0.z, u4.z), x3 = fmaf(q.w, e0.w, u4.w);
            float p01 = x0 * x1, p23 = x2 * x3;
            float num = fmaf(x0 + x1, p23, (x2 + x3) * p01);
            a0 = fmaf(num, rcp_fast(p01 * p23), a0);
        }
        {
            float x0 = fmaf(q.x, e1.x, u4.x), x1 = fmaf(q.y, e1.y, u4.y);
            float x2 = fmaf(q.z, e1.z, u4.z), x3 = fmaf(q.w, e1.w, u4.w);
            float p01 = x0 * x1, p23 = x2 * x3;
            float num = fmaf(x0 + x1, p23, (x2 + x3) * p01);
            a1 = fmaf(num, rcp_fast(p01 * p23), a1);
        }
        {
            float x0 = fmaf(q.x, e2.x, u4.x), x1 = fmaf(q.y, e2.y, u4.y);
            float x2 = fmaf(q.z, e2.z, u4.z), x3 = fmaf(q.w, e2.w, u4.w);
            float p01 = x0 * x1, p23 = x2 * x3;
            float num = fmaf(x0 + x1, p23, (x2 + x3) * p01);
            a2 = fmaf(num, rcp_fast(p01 * p23), a2);
        }
        {
            float x0 = fmaf(q.x, e3.x, u4.x), x1 = fmaf(q.y, e3.y, u4.y);
            float x2 = fmaf(q.z, e3.z, u4.z), x3 = fmaf(q.w, e3.w, u4.w);
            float p01 = x0 * x1, p23 = x2 * x3;
            float num = fmaf(x0 + x1, p23, (x2 + x3) * p01);
            a3 = fmaf(num, rcp_fast(p01 * p23), a3);
        }
    }

    // ---- Phase 2: softmax over j ----
    float p0 = __expf(-2.f * a0);
    float p1 = __expf(-2.f * a1);
    float p2 = __expf(-2.f * a2);
    float p3 = __expf(-2.f * a3);
    float r0 = p0, r1 = p1, r2 = p2, r3 = p3;
    #pragma unroll
    for (int off = 32; off > 0; off >>= 1) {
        r0 += __shfl_xor(r0, off, 64);
        r1 += __shfl_xor(r1, off, 64);
        r2 += __shfl_xor(r2, off, 64);
        r3 += __shfl_xor(r3, off, 64);
    }
    const int wv8 = j >> 6, ln = j & 63;
    if (ln == 0) at.red[wv8] = make_float4(r0, r1, r2, r3);
    __syncthreads();                                         // B2
    {
        float4 d0 = at.red[0], d1 = at.red[1], d2 = at.red[2], d3 = at.red[3];
        float4 d4 = at.red[4], d5 = at.red[5], d6 = at.red[6], d7 = at.red[7];
        float dx = ((d0.x + d1.x) + (d2.x + d3.x)) + ((d4.x + d5.x) + (d6.x + d7.x));
        float dy = ((d0.y + d1.y) + (d2.y + d3.y)) + ((d4.y + d5.y) + (d6.y + d7.y));
        float dz = ((d0.z + d1.z) + (d2.z + d3.z)) + ((d4.z + d5.z) + (d6.z + d7.z));
        float dw = ((d0.w + d1.w) + (d2.w + d3.w)) + ((d4.w + d5.w) + (d6.w + d7.w));
        float n0 = p0 * rcp_fast(dx);
        float n1 = p1 * rcp_fast(dy);
        float n2 = p2 * rcp_fast(dz);
        float n3 = p3 * rcp_fast(dw);
        float* ap = attn + ((size_t)b * SL + i0) * SL + j;   // coalesced
        ap[0]      = n0;
        ap[SL]     = n1;
        ap[2 * SL] = n2;
        ap[3 * SL] = n3;
        at.pT[j] = make_float4(n0, n1, n2, n3);
    }
    __syncthreads();                                         // B3

    // ---- Phase 3: out = attn @ inp; wave g covers j = g*64..g*64+63 ----
    {
        const int g  = j >> 6;                  // 8 waves
        const int dq = j & 31;                  // d-quad
        const int rh = (j >> 5) & 1;            // row pair
        const float4* inp4 = (const float4*)(inp) + (size_t)b * SL * 32;
        float4 accA = make_float4(0.f, 0.f, 0.f, 0.f);
        float4 accB = make_float4(0.f, 0.f, 0.f, 0.f);
        #pragma unroll 4
        for (int tt = 0; tt < 64; ++tt) {
            int jr = g * 64 + tt;
            float4 xv = inp4[jr * 32 + dq];                 // L2-local b128
            float2 pp = *((const float2*)&at.pT[jr] + rh);  // 2-addr LDS broadcast
            accA.x = fmaf(pp.x, xv.x, accA.x); accA.y = fmaf(pp.x, xv.y, accA.y);
            accA.z = fmaf(pp.x, xv.z, accA.z); accA.w = fmaf(pp.x, xv.w, accA.w);
            accB.x = fmaf(pp.y, xv.x, accB.x); accB.y = fmaf(pp.y, xv.y, accB.y);
            accB.z = fmaf(pp.y, xv.z, accB.z); accB.w = fmaf(pp.y, xv.w, accB.w);
        }
        *(float4*)&at.fin[((g * 4) + rh * 2 + 0) * BD + dq * 4] = accA;
        *(float4*)&at.fin[((g * 4) + rh * 2 + 1) * BD + dq * 4] = accB;
    }
    __syncthreads();                                         // B4
    {
        int row = j >> 7, d = j & 127;
        float s = 0.f;
        #pragma unroll
        for (int gg = 0; gg < 8; ++gg)
            s += at.fin[(gg * 4 + row) * BD + d];           // conflict-free
        out[((size_t)b * SL + i0 + row) * BD + d] = s;      // coalesced
    }
}

// ===================== fallback 3-kernel path (round-1, proven) =====================

__global__ __launch_bounds__(256) void k_tr(const float* __restrict__ Wu,
                                            const float* __restrict__ Ww,
                                            float* __restrict__ WuT,
                                            float* __restrict__ WwT) {
    int idx = blockIdx.x * 256 + threadIdx.x;
    int k = idx >> 7, o = idx & 127;
    WuT[idx] = Wu[o * BD + k];
    WwT[idx] = Ww[o * BD + k];
}

__global__ __launch_bounds__(256) void k_qk(const float* __restrict__ inp,
                                            const float* __restrict__ WuT,
                                            const float* __restrict__ WwT,
                                            float* __restrict__ Equ,
                                            float* __restrict__ Ekw) {
    __shared__ float sx[2][BD];
    const int t = threadIdx.x, m = t >> 7, o = t & 127;
    const int blk = blockIdx.x;
    const int x   = blk & 7;
    const int b   = x >> 1;
    const int rp  = (blk >> 3) * 2 + (x & 1);
    const int r0  = b * SL + rp * 2;
    const int l0  = rp * 2;

    sx[t >> 7][t & 127] = inp[(size_t)r0 * BD + t];
    __syncthreads();

    const float* WT = m ? WwT : WuT;
    float acc0 = 0.f, acc1 = 0.f;
    #pragma unroll 4
    for (int k = 0; k < BD; k += 4) {
        float w0 = WT[(k + 0) * BD + o];
        float w1 = WT[(k + 1) * BD + o];
        float w2 = WT[(k + 2) * BD + o];
        float w3 = WT[(k + 3) * BD + o];
        float4 x0 = *(const float4*)&sx[0][k];
        float4 x1 = *(const float4*)&sx[1][k];
        acc0 = fmaf(x0.x, w0, acc0); acc0 = fmaf(x0.y, w1, acc0);
        acc0 = fmaf(x0.z, w2, acc0); acc0 = fmaf(x0.w, w3, acc0);
        acc1 = fmaf(x1.x, w0, acc1); acc1 = fmaf(x1.y, w1, acc1);
        acc1 = fmaf(x1.z, w2, acc1); acc1 = fmaf(x1.w, w3, acc1);
    }

    if (m == 0) {
        size_t base = (((size_t)b * 32 + (o >> 2)) * SL + l0) * 4 + (o & 3);
        Equ[base]     = __expf(2.f * acc0);
        Equ[base + 4] = __expf(2.f * acc1);
    } else {
        Ekw[(size_t)(r0 + 0) * BD + o] = __expf(2.f * acc0);
        Ekw[(size_t)(r0 + 1) * BD + o] = __expf(2.f * acc1);
    }
}

__global__ __launch_bounds__(512, 4) void k_attn(const float* __restrict__ inp,
                                                 const float* __restrict__ Wv,
                                                 const float* __restrict__ Equ,
                                                 const float* __restrict__ Ekw,
                                                 float* __restrict__ out,
                                                 float* __restrict__ attn) {
    __shared__ float4 s_E2[32][4];
    __shared__ float4 s_u4[32];
    __shared__ float4 s_pT[SL];
    __shared__ float  s_fin[32 * BD];
    __shared__ float4 s_red[8];

    const int j   = threadIdx.x;
    const int blk = blockIdx.x;
    const int x   = blk & 7;
    const int b   = x >> 1;
    const int it  = (blk >> 3) * 2 + (x & 1);
    const int i0  = it * 4;

    if (j < BD) {
        const float* ek = Ekw + ((size_t)b * SL + i0) * BD + j;
        float u = rcp_fast(Wv[j]);
        int c = j >> 2, kk = j & 3;
        ((float*)&s_E2[c][0])[kk] = ek[0]      * u;
        ((float*)&s_E2[c][1])[kk] = ek[BD]     * u;
        ((float*)&s_E2[c][2])[kk] = ek[2 * BD] * u;
        ((float*)&s_E2[c][3])[kk] = ek[3 * BD] * u;
        ((float*)&s_u4[c])[kk]    = u;
    }
    __syncthreads();

    const float4* equ4 = (const float4*)(Equ) + (size_t)b * 32 * SL;
    float a0 = 0.f, a1 = 0.f, a2 = 0.f, a3 = 0.f;
    #pragma unroll 4
    for (int c = 0; c < 32; ++c) {
        float4 q  = equ4[c * SL + j];
        float4 u4 = s_u4[c];
        float4 e0 = s_E2[c][0];
        float4 e1 = s_E2[c][1];
        float4 e2 = s_E2[c][2];
        float4 e3 = s_E2[c][3];
        {
            float x0 = fmaf(q.x, e0.x, u4.x), x1 = fmaf(q.y, e0.y, u4.y);
            float x2 = fmaf(q.z, e0.z, u4.z), x3 = fmaf(q.w, e0.w, u4.w);
            float p01 = x0 * x1, p23 = x2 * x3;
            a0 = fmaf(fmaf(x0 + x1, p23, (x2 + x3) * p01), rcp_fast(p01 * p23), a0);
        }
        {
            float x0 = fmaf(q.x, e1.x, u4.x), x1 = fmaf(q.y, e1.y, u4.y);
            float x2 = fmaf(q.z, e1.z, u4.z), x3 = fmaf(q.w, e1.w, u4.w);
            float p01 = x0 * x1, p23 = x2 * x3;
            a1 = fmaf(fmaf(x0 + x1, p23, (x2 + x3) * p01), rcp_fast(p01 * p23), a1);
        }
        {
            float x0 = fmaf(q.x, e2.x, u4.x), x1 = fmaf(q.y, e2.y, u4.y);
            float x2 = fmaf(q.z, e2.z, u4.z), x3 = fmaf(q.w, e2.w, u4.w);
            float p01 = x0 * x1, p23 = x2 * x3;
            a2 = fmaf(fmaf(x0 + x1, p23, (x2 + x3) * p01), rcp_fast(p01 * p23), a2);
        }
        {
            float x0 = fmaf(q.x, e3.x, u4.x), x1 = fmaf(q.y, e3.y, u4.y);
            float x2 = fmaf(q.z, e3.z, u4.z), x3 = fmaf(q.w, e3.w, u4.w);
            float p01 = x0 * x1, p23 = x2 * x3;
            a3 = fmaf(fmaf(x0 + x1, p23, (x2 + x3) * p01), rcp_fast(p01 * p23), a3);
        }
    }

    float p0 = __expf(-2.f * a0);
    float p1 = __expf(-2.f * a1);
    float p2 = __expf(-2.f * a2);
    float p3 = __expf(-2.f * a3);
    float r0 = p0, r1 = p1, r2 = p2, r3 = p3;
    #pragma unroll
    for (int off = 32; off > 0; off >>= 1) {
        r0 += __shfl_xor(r0, off, 64);
        r1 += __shfl_xor(r1, off, 64);
        r2 += __shfl_xor(r2, off, 64);
        r3 += __shfl_xor(r3, off, 64);
    }
    const int w = j >> 6, ln = j & 63;
    if (ln == 0) s_red[w] = make_float4(r0, r1, r2, r3);
    __syncthreads();
    float4 d0 = s_red[0], d1 = s_red[1], d2 = s_red[2], d3 = s_red[3];
    float4 d4 = s_red[4], d5 = s_red[5], d6 = s_red[6], d7 = s_red[7];
    float dx = ((d0.x + d1.x) + (d2.x + d3.x)) + ((d4.x + d5.x) + (d6.x + d7.x));
    float dy = ((d0.y + d1.y) + (d2.y + d3.y)) + ((d4.y + d5.y) + (d6.y + d7.y));
    float dz = ((d0.z + d1.z) + (d2.z + d3.z)) + ((d4.z + d5.z) + (d6.z + d7.z));
    float dw = ((d0.w + d1.w) + (d2.w + d3.w)) + ((d4.w + d5.w) + (d6.w + d7.w));
    float n0 = p0 * rcp_fast(dx);
    float n1 = p1 * rcp_fast(dy);
    float n2 = p2 * rcp_fast(dz);
    float n3 = p3 * rcp_fast(dw);
    float* ap = attn + ((size_t)b * SL + i0) * SL + j;
    ap[0]      = n0;
    ap[SL]     = n1;
    ap[2 * SL] = n2;
    ap[3 * SL] = n3;
    s_pT[j] = make_float4(n0, n1, n2, n3);
    __syncthreads();

    const int g  = j >> 6;
    const int dq = j & 31;
    const int rh = (j >> 5) & 1;
    const float4* inp4 = (const float4*)(inp) + (size_t)b * SL * 32;
    float4 accA = make_float4(0.f, 0.f, 0.f, 0.f);
    float4 accB = make_float4(0.f, 0.f, 0.f, 0.f);
    #pragma unroll 4
    for (int tt = 0; tt < 64; ++tt) {
        int jr = g * 64 + tt;
        float4 xv = inp4[jr * 32 + dq];
        float2 pp = *((const float2*)&s_pT[jr] + rh);
        accA.x = fmaf(pp.x, xv.x, accA.x); accA.y = fmaf(pp.x, xv.y, accA.y);
        accA.z = fmaf(pp.x, xv.z, accA.z); accA.w = fmaf(pp.x, xv.w, accA.w);
        accB.x = fmaf(pp.y, xv.x, accB.x); accB.y = fmaf(pp.y, xv.y, accB.y);
        accB.z = fmaf(pp.y, xv.z, accB.z); accB.w = fmaf(pp.y, xv.w, accB.w);
    }
    *(float4*)&s_fin[((g * 4) + rh * 2 + 0) * BD + dq * 4] = accA;
    *(float4*)&s_fin[((g * 4) + rh * 2 + 1) * BD + dq * 4] = accB;
    __syncthreads();
    {
        int row = j >> 7, d = j & 127;
        float s = 0.f;
        #pragma unroll
        for (int gg = 0; gg < 8; ++gg)
            s += s_fin[(gg * 4 + row) * BD + d];
        out[((size_t)b * SL + i0 + row) * BD + d] = s;
    }
}

extern "C" void kernel_launch(void* const* d_in, const int* in_sizes, int n_in,
                              void* d_out, int out_size, void* d_ws, size_t ws_size,
                              hipStream_t stream) {
    const float* inp = (const float*)d_in[0];
    const float* Wu  = (const float*)d_in[1];
    const float* Ww  = (const float*)d_in[2];
    const float* Wv  = (const float*)d_in[3];

    float* out  = (float*)d_out;
    float* attn = out + (size_t)NB * SL * BD;     // out (B,L,D) then attn (B,L,L)

    float* ws   = (float*)d_ws;
    float* Equ  = ws;                             // (B, D/4, L, 4) packed exp(2*qu)
    float* Ekw  = Equ + (size_t)NB * BD * SL;     // (B, L, D) exp(2*kw)
    float* WuT  = Ekw + (size_t)NB * SL * BD;     // fallback only
    float* WwT  = WuT + BD * BD;                  // fallback only

    void* args[] = {(void*)&inp, (void*)&Wu, (void*)&Ww, (void*)&Wv,
                    (void*)&Equ, (void*)&Ekw, (void*)&out, (void*)&attn};
    hipError_t err = hipLaunchCooperativeKernel((const void*)k_fused,
                                                dim3(NB * SL / 4), dim3(512),
                                                args, 0, stream);
    if (err != hipSuccess) {
        // graph-capture or residency rejection -> proven 3-kernel path
        k_tr  <<<BD * BD / 256, 256, 0, stream>>>(Wu, Ww, WuT, WwT);
        k_qk  <<<NB * SL / 2, 256, 0, stream>>>(inp, WuT, WwT, Equ, Ekw);
        k_attn<<<NB * SL / 4, 512, 0, stream>>>(inp, Wv, Equ, Ekw, out, attn);
    }
}

// Round 3
// 87.772 us; speedup vs baseline: 2.3078x; 2.3078x over previous
//
#include <hip/hip_runtime.h>

#define BD 128   // D
#define SL 512   // L
#define NB 4     // B

__device__ __forceinline__ float rcp_fast(float x) { return __builtin_amdgcn_rcpf(x); }

// K1: transpose-free QK (proven in round 2's fused kernel, now standalone).
// qu = inp@Wu.T, kw = inp@Ww.T. 512 blocks = 4 batches x 128 jobs.
// Job = {m: Wu/Ww, o-slab of 16, row-chunk of 64}. Wave = 64 rows (lanes),
// 2 outputs o per wave -> W rows consumed row-contiguous via wave-uniform
// scalar loads; NO weight transpose kernel needed.
// XCD pinning: batch b on XCD pair {2b,2b+1} so Equ/Ekw land in the L2
// that k_attn (same pinning) reads them from.
__global__ __launch_bounds__(512, 4) void k_qk2(const float* __restrict__ inp,
                                                const float* __restrict__ Wu,
                                                const float* __restrict__ Ww,
                                                float* __restrict__ Equ,
                                                float* __restrict__ Ekw) {
    __shared__ float sx[64][130];   // 64 staged rows, pad->2-way bank max (free)
    __shared__ float se[16][65];    // transpose stage for coalesced stores
    const int t   = threadIdx.x;
    const int blk = blockIdx.x;
    const int x   = blk & 7;                     // XCD (round-robin heuristic)
    const int b   = x >> 1;                      // batch pinned to XCD pair
    const int jb  = ((blk >> 3) << 1) | (x & 1); // 0..127 within batch
    const int m   = jb & 1;                      // 0: Wu->Equ, 1: Ww->Ekw
    const int o0  = ((jb >> 1) & 7) << 4;        // o slab base 0,16,..,112
    const int rc  = jb >> 4;                     // row chunk 0..7
    const int R0  = b * SL + rc * 64;            // global row base

    #pragma unroll
    for (int c = 0; c < 16; ++c) {               // stage 64 rows, coalesced
        int lin = c * 512 + t;
        sx[lin >> 7][lin & 127] = inp[(size_t)R0 * BD + lin];
    }
    __syncthreads();

    const int w = t >> 6, l = t & 63;            // wave id, lane = row
    const int ou = __builtin_amdgcn_readfirstlane(o0 + (w << 1));
    const float* __restrict__ Wm = m ? Ww : Wu;
    const float* __restrict__ W0 = Wm + (size_t)ou * BD;   // row-contiguous!
    const float* __restrict__ W1 = W0 + BD;
    float acc0 = 0.f, acc1 = 0.f;
    #pragma unroll 8
    for (int k = 0; k < BD; k += 2) {
        float2 xv = *(const float2*)&sx[l][k];   // b64, 2-way bank = free
        float wa0 = W0[k], wb0 = W0[k + 1];      // wave-uniform scalar loads
        float wa1 = W1[k], wb1 = W1[k + 1];
        acc0 = fmaf(xv.x, wa0, acc0); acc0 = fmaf(xv.y, wb0, acc0);
        acc1 = fmaf(xv.x, wa1, acc1); acc1 = fmaf(xv.y, wb1, acc1);
    }
    se[(w << 1) + 0][l] = __expf(2.f * acc0);    // LDS transpose stage
    se[(w << 1) + 1][l] = __expf(2.f * acc1);
    __syncthreads();

    if (m) {
        // Ekw[b,row][o]: 16-float row segments, coalesced per wave
        #pragma unroll
        for (int ph = 0; ph < 2; ++ph) {
            int e   = ph * 512 + t;
            int row = e >> 4, ol = e & 15;
            Ekw[(size_t)(R0 + row) * BD + o0 + ol] = se[ol][row];
        }
    } else {
        // Equ[b][c][j][kk] packed layout, coalesced 256B runs
        float* Eb = Equ + (((size_t)b * 32 + (o0 >> 2)) * SL + rc * 64) * 4;
        #pragma unroll
        for (int ph = 0; ph < 2; ++ph) {
            int e  = ph * 512 + t;
            int cL = e >> 8, lj = (e >> 2) & 63, kk = e & 3;
            Eb[((size_t)cL * SL + lj) * 4 + kk] = se[cL * 4 + kk][lj];
        }
    }
}

// K2: block = (b, 4 query rows), 512 threads = one thread per key j (P1/P2).
// score_ij = const - 2*sum_d 1/x_d, x_d = fma(Equ_jd, Ekw_id/wv_d, 1/wv_d).
// P3 v2: 16 groups (wave x j-half of 32); each lane accumulates ALL 4 rows
// (float4) for its d-quad -> every (j, d-quad) of inp(b) read exactly ONCE
// per block (was twice): L2 traffic 512->256 KB/block, loads/lane halved.
__global__ __launch_bounds__(512, 4) void k_attn(const float* __restrict__ inp,
                                                 const float* __restrict__ Wv,
                                                 const float* __restrict__ Equ,
                                                 const float* __restrict__ Ekw,
                                                 float* __restrict__ out,
                                                 float* __restrict__ attn) {
    __shared__ float4 s_E2[32][4];     // 2 KB  [c][i]: Ekw[i0+i][4c..4c+3] * u
    __shared__ float4 s_u4[32];        // 0.5KB u[4c..4c+3] = 1/wv
    __shared__ float4 s_pT[SL];        // 8 KB  attn row-quad per j
    __shared__ float4 s_fin4[16 * 4 * 32];  // 32 KB P3 partials [gi][row][dq]
    __shared__ float4 s_red[8];        // per-wave softmax partial sums

    const int j   = threadIdx.x;       // key index 0..511
    const int blk = blockIdx.x;
    const int x   = blk & 7;           // XCD
    const int b   = x >> 1;            // batch pinned to XCD pair
    const int it  = ((blk >> 3) << 1) | (x & 1);   // i-tile 0..127
    const int i0  = it * 4;

    if (j < BD) {
        const float* ek = Ekw + ((size_t)b * SL + i0) * BD + j;
        float u = rcp_fast(Wv[j]);
        int c = j >> 2, kk = j & 3;
        ((float*)&s_E2[c][0])[kk] = ek[0]      * u;
        ((float*)&s_E2[c][1])[kk] = ek[BD]     * u;
        ((float*)&s_E2[c][2])[kk] = ek[2 * BD] * u;
        ((float*)&s_E2[c][3])[kk] = ek[3 * BD] * u;
        ((float*)&s_u4[c])[kk]    = u;
    }
    __syncthreads();                                         // B1

    // ---- Phase 1: a_i = sum_d 1/x_d, fully in registers, quad-rcp ----
    const float4* equ4 = (const float4*)(Equ) + (size_t)b * 32 * SL;
    float a0 = 0.f, a1 = 0.f, a2 = 0.f, a3 = 0.f;
    #pragma unroll 4
    for (int c = 0; c < 32; ++c) {
        float4 q  = equ4[c * SL + j];      // coalesced, L2-local
        float4 u4 = s_u4[c];               // wave-uniform b128 broadcasts
        float4 e0 = s_E2[c][0];
        float4 e1 = s_E2[c][1];
        float4 e2 = s_E2[c][2];
        float4 e3 = s_E2[c][3];
        {
            float x0 = fmaf(q.x, e0.x, u4.x), x1 = fmaf(q.y, e0.y, u4.y);
            float x2 = fmaf(q.z, e0.z, u4.z), x3 = fmaf(q.w, e0.w, u4.w);
            float p01 = x0 * x1, p23 = x2 * x3;
            a0 = fmaf(fmaf(x0 + x1, p23, (x2 + x3) * p01), rcp_fast(p01 * p23), a0);
        }
        {
            float x0 = fmaf(q.x, e1.x, u4.x), x1 = fmaf(q.y, e1.y, u4.y);
            float x2 = fmaf(q.z, e1.z, u4.z), x3 = fmaf(q.w, e1.w, u4.w);
            float p01 = x0 * x1, p23 = x2 * x3;
            a1 = fmaf(fmaf(x0 + x1, p23, (x2 + x3) * p01), rcp_fast(p01 * p23), a1);
        }
        {
            float x0 = fmaf(q.x, e2.x, u4.x), x1 = fmaf(q.y, e2.y, u4.y);
            float x2 = fmaf(q.z, e2.z, u4.z), x3 = fmaf(q.w, e2.w, u4.w);
            float p01 = x0 * x1, p23 = x2 * x3;
            a2 = fmaf(fmaf(x0 + x1, p23, (x2 + x3) * p01), rcp_fast(p01 * p23), a2);
        }
        {
            float x0 = fmaf(q.x, e3.x, u4.x), x1 = fmaf(q.y, e3.y, u4.y);
            float x2 = fmaf(q.z, e3.z, u4.z), x3 = fmaf(q.w, e3.w, u4.w);
            float p01 = x0 * x1, p23 = x2 * x3;
            a3 = fmaf(fmaf(x0 + x1, p23, (x2 + x3) * p01), rcp_fast(p01 * p23), a3);
        }
    }

    // ---- Phase 2: softmax over j (no max-shift; scores bounded, fp32-safe) ----
    float p0 = __expf(-2.f * a0);
    float p1 = __expf(-2.f * a1);
    float p2 = __expf(-2.f * a2);
    float p3 = __expf(-2.f * a3);
    float r0 = p0, r1 = p1, r2 = p2, r3 = p3;
    #pragma unroll
    for (int off = 32; off > 0; off >>= 1) {
        r0 += __shfl_xor(r0, off, 64);
        r1 += __shfl_xor(r1, off, 64);
        r2 += __shfl_xor(r2, off, 64);
        r3 += __shfl_xor(r3, off, 64);
    }
    const int w8 = j >> 6, ln0 = j & 63;
    if (ln0 == 0) s_red[w8] = make_float4(r0, r1, r2, r3);
    __syncthreads();                                         // B2
    {
        float4 d0 = s_red[0], d1 = s_red[1], d2 = s_red[2], d3 = s_red[3];
        float4 d4 = s_red[4], d5 = s_red[5], d6 = s_red[6], d7 = s_red[7];
        float dx = ((d0.x + d1.x) + (d2.x + d3.x)) + ((d4.x + d5.x) + (d6.x + d7.x));
        float dy = ((d0.y + d1.y) + (d2.y + d3.y)) + ((d4.y + d5.y) + (d6.y + d7.y));
        float dz = ((d0.z + d1.z) + (d2.z + d3.z)) + ((d4.z + d5.z) + (d6.z + d7.z));
        float dw = ((d0.w + d1.w) + (d2.w + d3.w)) + ((d4.w + d5.w) + (d6.w + d7.w));
        float n0 = p0 * rcp_fast(dx);
        float n1 = p1 * rcp_fast(dy);
        float n2 = p2 * rcp_fast(dz);
        float n3 = p3 * rcp_fast(dw);
        float* ap = attn + ((size_t)b * SL + i0) * SL + j;   // coalesced
        ap[0]      = n0;
        ap[SL]     = n1;
        ap[2 * SL] = n2;
        ap[3 * SL] = n3;
        s_pT[j] = make_float4(n0, n1, n2, n3);
    }
    __syncthreads();                                         // B3

    // ---- Phase 3 v2: out = attn @ inp; group gi = (wave, j-half) covers 32 j,
    //      lane owns d-quad dq and accumulates all 4 query rows ----
    {
        const int g  = j >> 6;              // 8 waves
        const int ln = j & 63;
        const int dq = ln & 31;             // d-quad 0..31
        const int jh = ln >> 5;             // j-half 0/1
        const int gi = g * 2 + jh;          // group 0..15, covers j = gi*32..+31
        const float4* inp4 = (const float4*)(inp) + (size_t)b * SL * 32;
        float4 A0 = make_float4(0.f, 0.f, 0.f, 0.f);
        float4 A1 = A0, A2 = A0, A3 = A0;
        #pragma unroll 4
        for (int tt = 0; tt < 32; ++tt) {
            int jr = gi * 32 + tt;
            float4 xv = inp4[jr * 32 + dq];   // L2-local b128, each pair ONCE
            float4 pp = s_pT[jr];             // 2-addr/wave LDS b128 broadcast
            A0.x = fmaf(pp.x, xv.x, A0.x); A0.y = fmaf(pp.x, xv.y, A0.y);
            A0.z = fmaf(pp.x, xv.z, A0.z); A0.w = fmaf(pp.x, xv.w, A0.w);
            A1.x = fmaf(pp.y, xv.x, A1.x); A1.y = fmaf(pp.y, xv.y, A1.y);
            A1.z = fmaf(pp.y, xv.z, A1.z); A1.w = fmaf(pp.y, xv.w, A1.w);
            A2.x = fmaf(pp.z, xv.x, A2.x); A2.y = fmaf(pp.z, xv.y, A2.y);
            A2.z = fmaf(pp.z, xv.z, A2.z); A2.w = fmaf(pp.z, xv.w, A2.w);
            A3.x = fmaf(pp.w, xv.x, A3.x); A3.y = fmaf(pp.w, xv.y, A3.y);
            A3.z = fmaf(pp.w, xv.z, A3.z); A3.w = fmaf(pp.w, xv.w, A3.w);
        }
        s_fin4[((gi * 4) + 0) * 32 + dq] = A0;   // 512B runs, conflict-free
        s_fin4[((gi * 4) + 1) * 32 + dq] = A1;
        s_fin4[((gi * 4) + 2) * 32 + dq] = A2;
        s_fin4[((gi * 4) + 3) * 32 + dq] = A3;
    }
    __syncthreads();                                         // B4
    {
        const float* fin = (const float*)s_fin4;
        int row = j >> 7, d = j & 127;
        float s = 0.f;
        #pragma unroll
        for (int gg = 0; gg < 16; ++gg)
            s += fin[(gg * 4 + row) * BD + d];             // conflict-free
        out[((size_t)b * SL + i0 + row) * BD + d] = s;     // coalesced
    }
}

extern "C" void kernel_launch(void* const* d_in, const int* in_sizes, int n_in,
                              void* d_out, int out_size, void* d_ws, size_t ws_size,
                              hipStream_t stream) {
    const float* inp = (const float*)d_in[0];
    const float* Wu  = (const float*)d_in[1];
    const float* Ww  = (const float*)d_in[2];
    const float* Wv  = (const float*)d_in[3];

    float* out  = (float*)d_out;
    float* attn = out + (size_t)NB * SL * BD;     // out (B,L,D) then attn (B,L,L)

    float* ws   = (float*)d_ws;
    float* Equ  = ws;                             // (B, D/4, L, 4) packed exp(2*qu)
    float* Ekw  = Equ + (size_t)NB * BD * SL;     // (B, L, D) exp(2*kw)

    k_qk2 <<<NB * SL / 4, 512, 0, stream>>>(inp, Wu, Ww, Equ, Ekw);
    k_attn<<<NB * SL / 4, 512, 0, stream>>>(inp, Wv, Equ, Ekw, out, attn);
}